// Round 2
// baseline (248.025 us; speedup 1.0000x reference)
//
#include <hip/hip_runtime.h>

// SegmentationAugmentation: fused affine-grid + trilinear grid_sample (border,
// align_corners=False) for input (float out) and label (bool-as-float out).
//
// R5: R4 post-mortem — flat vs R3 because the packed-accumulate win was offset
// by reg-staging (vs global_load_lds DMA) and the dominant VALU cost is the
// block-uniform x/y path (~40 ops, redundantly per thread; CDNA has no scalar
// float pipe). Fix: hoist all uniform/separable float math into tables built
// by a tiny helper kernel each launch (graph-capture-safe, ~5 us):
//   ws[0..1023]      : z-table, 128 x {iz0, fz}  (per-thread load, L1-resident)
//   ws[1024..263167] : xy-table, 16384 x {ix0, iy0, fx, fy} (block-uniform ->
//                      compiler emits s_load_dwordx4; ix1/iy1/row-base math
//                      becomes SALU, parallel issue with VALU)
// Main kernel restores R3's global_load_lds direct-DMA staging (R4's
// reg-staging was a measured regression path) and keeps R4's validated
// z-edge-select elimination: read s[iz0], s[iz0+1] directly; at iz0==127,
// fz==+0 so all z1-plane weights are +0 and the one-past value (next row's
// z=0, or the zeroed guard dword for the last row) contributes +-0 — bit-
// identical to the reference's +0*s[127] (R4 passed absmax 0.0 with this).
//
// CORRECTNESS-CRITICAL: label output is a hard comparator (acc > 0.5) with
// voxels ~0.5 ulp from the boundary; all float math must stay bit-exact vs
// numpy: contract(off) in BOTH kernels, x/y/z paths copied verbatim into the
// table kernel, w = (wz*wy)*wx, reference corner accumulation order (z outer,
// y mid, x inner). Tables only move where the same bits are computed.

#define NV 128
#define TOTAL (8 * NV * NV * NV)

// ---- table-builder: block 128 = z-table, blocks 0..127 = xy-table ----
__global__ __launch_bounds__(128) void seg_aug_tables(
    const float* __restrict__ T, float* __restrict__ ws)
{
#pragma clang fp contract(off)
    const int t = threadIdx.x;
    if (blockIdx.x == 128) {
        // z-table entry t = {iz0, fz}; verbatim R3 z path
        float p4 = (2.0f * (float)t + 1.0f) / 128.0f - 1.0f;
        float uz = T[10] * p4 + T[11];
        float gz = ((uz + 1.0f) * 128.0f - 1.0f) * 0.5f;
        gz = fminf(fmaxf(gz, 0.0f), 127.0f);
        float fz0f = floorf(gz);
        float fz = gz - fz0f;
        int2 v;
        v.x = (int)fz0f;
        v.y = __float_as_int(fz);
        ((int2*)ws)[t] = v;
    } else {
        const int idx = blockIdx.x * 128 + t;   // 0..16383
        const int o3 = idx & (NV - 1);
        const int o2 = idx >> 7;
        // verbatim R3 x/y path
        float p2 = (2.0f * (float)o2 + 1.0f) / 128.0f - 1.0f;
        float p3 = (2.0f * (float)o3 + 1.0f) / 128.0f - 1.0f;
        float ux = (T[0] * p2 + T[1] * p3) + T[3];
        float uy = (T[4] * p2 + T[5] * p3) + T[7];
        float gx = ((ux + 1.0f) * 128.0f - 1.0f) * 0.5f;
        float gy = ((uy + 1.0f) * 128.0f - 1.0f) * 0.5f;
        gx = fminf(fmaxf(gx, 0.0f), 127.0f);
        gy = fminf(fmaxf(gy, 0.0f), 127.0f);
        float fx0f = floorf(gx), fy0f = floorf(gy);
        int4 v;
        v.x = (int)fx0f;
        v.y = (int)fy0f;
        v.z = __float_as_int(gx - fx0f);
        v.w = __float_as_int(gy - fy0f);
        ((int4*)(ws + 256))[idx] = v;           // +1024 bytes
    }
}

__global__ __launch_bounds__(128) void seg_aug_kernel(
    const float* __restrict__ in,
    const float* __restrict__ lab,
    const float* __restrict__ ws,  // tables (read-only here)
    float* __restrict__ out_in,
    float* __restrict__ out_lab)
{
#pragma clang fp contract(off)
    // rows: in{x0y0,x0y1,x1y0,x1y1}, lab{same}; +1 zeroed guard dword so the
    // last row's iz0==127 "z+1" read is finite (weight is +0 there).
    __shared__ __align__(16) float s[8 * NV + 1];

    const int t = threadIdx.x;                   // 0..127 = o4
    const int b = blockIdx.x >> 14;

    // ---- block-uniform x/y from table (scalar load) ----
    const int4 e = ((const int4*)(ws + 256))[blockIdx.x & 16383];
    const int ix0 = __builtin_amdgcn_readfirstlane(e.x);
    const int iy0 = __builtin_amdgcn_readfirstlane(e.y);
    const float fx = __int_as_float(e.z);
    const float fy = __int_as_float(e.w);
    const int ix1 = min(ix0 + 1, NV - 1);
    const int iy1 = min(iy0 + 1, NV - 1);

    // ---- per-thread z from table ----
    const int2 ze = ((const int2*)ws)[t];
    const int iz0 = ze.x;
    const float fz = __int_as_float(ze.y);

    // ---- stage 8 rows into LDS via DMA (R3 pattern) ----
    const size_t bbase = (size_t)b << 21;        // b * 128^3
    {
        const int rid = t >> 5;                  // 0..3
        const int seg = t & 31;
        const int ixS = (rid & 2) ? ix1 : ix0;
        const int iyS = (rid & 1) ? iy1 : iy0;
        const int off = (ixS * NV + iyS) * NV + seg * 4;
        __builtin_amdgcn_global_load_lds(in  + bbase + off, &s[t * 4],       16, 0, 0);
        __builtin_amdgcn_global_load_lds(lab + bbase + off, &s[512 + t * 4], 16, 0, 0);
    }
    if (t == 0) s[8 * NV] = 0.0f;                // finite guard

    const float wz0 = 1.0f - fz, wz1 = fz;
    const float wx0 = 1.0f - fx, wx1 = fx;
    const float wy0 = 1.0f - fy, wy1 = fy;

    __syncthreads();

    // direct pair reads at iz0 / iz0+1 (adjacent dwords -> ds_read2_b32)
    const float* rp = s + iz0;
    float ia00 = rp[0 * NV], ib00 = rp[0 * NV + 1];   // in,  (x0,y0)
    float ia01 = rp[1 * NV], ib01 = rp[1 * NV + 1];   // in,  (x0,y1)
    float ia10 = rp[2 * NV], ib10 = rp[2 * NV + 1];   // in,  (x1,y0)
    float ia11 = rp[3 * NV], ib11 = rp[3 * NV + 1];   // in,  (x1,y1)
    float la00 = rp[4 * NV], lb00 = rp[4 * NV + 1];   // lab, (x0,y0)
    float la01 = rp[5 * NV], lb01 = rp[5 * NV + 1];
    float la10 = rp[6 * NV], lb10 = rp[6 * NV + 1];
    float la11 = rp[7 * NV], lb11 = rp[7 * NV + 1];

    // weights, reference order: w = (wz*wy)*wx
    float tz0y0 = wz0 * wy0, tz0y1 = wz0 * wy1;
    float tz1y0 = wz1 * wy0, tz1y1 = wz1 * wy1;
    float w1 = tz0y0 * wx0, w2 = tz0y0 * wx1;
    float w3 = tz0y1 * wx0, w4 = tz0y1 * wx1;
    float w5 = tz1y0 * wx0, w6 = tz1y0 * wx1;
    float w7 = tz1y1 * wx0, w8 = tz1y1 * wx1;

    // reference accumulation order: z outer, y mid, x inner
    float acc_i = 0.0f;
    acc_i = acc_i + ia00 * w1;
    acc_i = acc_i + ia10 * w2;
    acc_i = acc_i + ia01 * w3;
    acc_i = acc_i + ia11 * w4;
    acc_i = acc_i + ib00 * w5;
    acc_i = acc_i + ib10 * w6;
    acc_i = acc_i + ib01 * w7;
    acc_i = acc_i + ib11 * w8;

    float acc_l = 0.0f;
    acc_l = acc_l + la00 * w1;
    acc_l = acc_l + la10 * w2;
    acc_l = acc_l + la01 * w3;
    acc_l = acc_l + la11 * w4;
    acc_l = acc_l + lb00 * w5;
    acc_l = acc_l + lb10 * w6;
    acc_l = acc_l + lb01 * w7;
    acc_l = acc_l + lb11 * w8;

    const int oidx = blockIdx.x * NV + t;        // (b,o2,o3,o4) flat
    out_in[oidx]  = acc_i;
    out_lab[oidx] = (acc_l > 0.5f) ? 1.0f : 0.0f;
}

extern "C" void kernel_launch(void* const* d_in, const int* in_sizes, int n_in,
                              void* d_out, int out_size, void* d_ws, size_t ws_size,
                              hipStream_t stream) {
    const float* in  = (const float*)d_in[0];
    const float* lab = (const float*)d_in[1];
    const float* T   = (const float*)d_in[2];
    float* out_in  = (float*)d_out;
    float* out_lab = (float*)d_out + TOTAL;
    float* ws      = (float*)d_ws;              // needs 263168 B (257 KB)

    seg_aug_tables<<<dim3(129), dim3(128), 0, stream>>>(T, ws);
    seg_aug_kernel<<<dim3(TOTAL / 128), dim3(128), 0, stream>>>(
        in, lab, ws, out_in, out_lab);
}

// Round 3
// 237.739 us; speedup vs baseline: 1.0433x; 1.0433x over previous
//
#include <hip/hip_runtime.h>

// SegmentationAugmentation: fused affine-grid + trilinear grid_sample (border,
// align_corners=False) for input (float out) and label (bool-as-float out).
//
// R6: R5 post-mortem — VALUBusy 70->41% but time flat at ~88us; R3/R4/R5 (all
// structurally different inner loops) pin at 86-89us with no pipe saturated
// (HBM 47% of achievable, VALU 41%, LDS trivial). The shared structure is
// 131072 tiny 128-thread WGs (~0.62 WG/cycle sustained dispatch) each with a
// full vmcnt(0) drain + __syncthreads coupling its 2 waves. R6 removes all of
// it: ONE WAVE PER OUTPUT COLUMN, fully independent.
//   - wave stages all 8 of its rows (4KB) itself: 4x global_load_lds, each
//     covering 2 rows (lanes 0-31 -> row A, lanes 32-63 -> row B; DMA dest is
//     wave-uniform base + lane*16, so rows land linearly).
//   - wave-local s_waitcnt vmcnt(0); NO __syncthreads anywhere.
//   - each lane computes 2 outputs (z=l, z=l+64), math verbatim R5 per z.
//   - block = 512 thr = 8 independent waves = 8 columns; grid 131072->16384.
//   - LDS 8*4112B = 32.9KB -> 4 blocks/CU = 32 waves/CU (full occupancy).
// Tables (R5, validated bit-exact): ws[0..255] z-table 128x{iz0,fz};
// ws+256: xy-table 16384x{ix0,iy0,fx,fy} (block... column-uniform s_load).
//
// Keeps R4/R5's validated z-edge elimination: read s[iz0], s[iz0+1] directly;
// at iz0==127 fz==+0 so z1-plane weights are +0 and the one-past value (next
// row's z=0, or the per-wave zeroed guard dword for the last row) contributes
// +-0 — bit-identical to the reference's +0*s[127] (absmax 0.0 in R4/R5).
//
// CORRECTNESS-CRITICAL: label output is a hard comparator (acc > 0.5) with
// voxels ~0.5 ulp from the boundary; all float math must stay bit-exact vs
// numpy: contract(off) in BOTH kernels, x/y/z paths verbatim in the table
// kernel, w = (wz*wy)*wx, reference corner accumulation order (z outer, y
// mid, x inner). Restructuring only changes where/when identical bits flow.

#define NV 128
#define TOTAL (8 * NV * NV * NV)
#define WPB 8                 // waves (= columns) per block
#define WSTRIDE 1028          // floats per wave LDS region: 1024 data + guard + pad (16B-aligned)

// ---- table-builder: block 128 = z-table, blocks 0..127 = xy-table ----
__global__ __launch_bounds__(128) void seg_aug_tables(
    const float* __restrict__ T, float* __restrict__ ws)
{
#pragma clang fp contract(off)
    const int t = threadIdx.x;
    if (blockIdx.x == 128) {
        // z-table entry t = {iz0, fz}; verbatim R3 z path
        float p4 = (2.0f * (float)t + 1.0f) / 128.0f - 1.0f;
        float uz = T[10] * p4 + T[11];
        float gz = ((uz + 1.0f) * 128.0f - 1.0f) * 0.5f;
        gz = fminf(fmaxf(gz, 0.0f), 127.0f);
        float fz0f = floorf(gz);
        float fz = gz - fz0f;
        int2 v;
        v.x = (int)fz0f;
        v.y = __float_as_int(fz);
        ((int2*)ws)[t] = v;
    } else {
        const int idx = blockIdx.x * 128 + t;   // 0..16383
        const int o3 = idx & (NV - 1);
        const int o2 = idx >> 7;
        // verbatim R3 x/y path
        float p2 = (2.0f * (float)o2 + 1.0f) / 128.0f - 1.0f;
        float p3 = (2.0f * (float)o3 + 1.0f) / 128.0f - 1.0f;
        float ux = (T[0] * p2 + T[1] * p3) + T[3];
        float uy = (T[4] * p2 + T[5] * p3) + T[7];
        float gx = ((ux + 1.0f) * 128.0f - 1.0f) * 0.5f;
        float gy = ((uy + 1.0f) * 128.0f - 1.0f) * 0.5f;
        gx = fminf(fmaxf(gx, 0.0f), 127.0f);
        gy = fminf(fmaxf(gy, 0.0f), 127.0f);
        float fx0f = floorf(gx), fy0f = floorf(gy);
        int4 v;
        v.x = (int)fx0f;
        v.y = (int)fy0f;
        v.z = __float_as_int(gx - fx0f);
        v.w = __float_as_int(gy - fy0f);
        ((int4*)(ws + 256))[idx] = v;           // +1024 bytes
    }
}

__global__ __launch_bounds__(512) void seg_aug_kernel(
    const float* __restrict__ in,
    const float* __restrict__ lab,
    const float* __restrict__ ws,  // tables (read-only here)
    float* __restrict__ out_in,
    float* __restrict__ out_lab)
{
#pragma clang fp contract(off)
    __shared__ __align__(16) float s[WPB * WSTRIDE];

    const int t = threadIdx.x;
    const int l = t & 63;                                   // lane
    const int w = __builtin_amdgcn_readfirstlane(t >> 6);   // wave id (uniform)
    const int col = (blockIdx.x << 3) | w;                  // global column
    const int b = col >> 14;

    // ---- column-uniform x/y from table (scalar load) ----
    const int4 e = ((const int4*)(ws + 256))[col & 16383];
    const int ix0 = __builtin_amdgcn_readfirstlane(e.x);
    const int iy0 = __builtin_amdgcn_readfirstlane(e.y);
    const float fx = __int_as_float(e.z);
    const float fy = __int_as_float(e.w);
    const int ix1 = min(ix0 + 1, NV - 1);
    const int iy1 = min(iy0 + 1, NV - 1);
    const int r00 = (ix0 * NV + iy0) * NV;   // row byte layout: rid = {00,01,10,11}
    const int r01 = (ix0 * NV + iy1) * NV;
    const int r10 = (ix1 * NV + iy0) * NV;
    const int r11 = (ix1 * NV + iy1) * NV;

    // ---- stage 8 rows (4KB) for THIS wave; no cross-wave sharing ----
    // inst A: lanes 0-31 -> row00, 32-63 -> row01 (dest floats 0..255)
    // inst B: lanes 0-31 -> row10, 32-63 -> row11 (dest floats 256..511)
    const int segoff = (l & 31) * 4;
    const int offA = ((l < 32) ? r00 : r01) + segoff;
    const int offB = ((l < 32) ? r10 : r11) + segoff;
    const size_t bbase = (size_t)b << 21;    // b * 128^3
    const float* ibp = in  + bbase;
    const float* lbp = lab + bbase;
    float* sw = &s[w * WSTRIDE];
    __builtin_amdgcn_global_load_lds(ibp + offA, sw,       16, 0, 0);
    __builtin_amdgcn_global_load_lds(ibp + offB, sw + 256, 16, 0, 0);
    __builtin_amdgcn_global_load_lds(lbp + offA, sw + 512, 16, 0, 0);
    __builtin_amdgcn_global_load_lds(lbp + offB, sw + 768, 16, 0, 0);
    if (l == 0) sw[1024] = 0.0f;             // finite guard for iz0==127 pair read

    // ---- per-lane z entries (z = l and l+64), overlap with DMA latency ----
    const int2 ze0 = ((const int2*)ws)[l];
    const int2 ze1 = ((const int2*)ws)[l + 64];

    const float wx0 = 1.0f - fx, wx1 = fx;
    const float wy0 = 1.0f - fy, wy1 = fy;

    // wave-local completion of the 4 DMA loads; no barrier needed.
    asm volatile("s_waitcnt vmcnt(0)" ::: "memory");
    __builtin_amdgcn_sched_barrier(0);

    const int obase = col * NV;

    #define DO_Z(ZE, ZOFF)                                                    \
    {                                                                         \
        const int iz0 = (ZE).x;                                               \
        const float fz = __int_as_float((ZE).y);                              \
        const float wz0 = 1.0f - fz, wz1 = fz;                                \
        const float* rp = sw + iz0;                                           \
        float ia00 = rp[0 * NV], ib00 = rp[0 * NV + 1];                       \
        float ia01 = rp[1 * NV], ib01 = rp[1 * NV + 1];                       \
        float ia10 = rp[2 * NV], ib10 = rp[2 * NV + 1];                       \
        float ia11 = rp[3 * NV], ib11 = rp[3 * NV + 1];                       \
        float la00 = rp[4 * NV], lb00 = rp[4 * NV + 1];                       \
        float la01 = rp[5 * NV], lb01 = rp[5 * NV + 1];                       \
        float la10 = rp[6 * NV], lb10 = rp[6 * NV + 1];                       \
        float la11 = rp[7 * NV], lb11 = rp[7 * NV + 1];                       \
        float tz0y0 = wz0 * wy0, tz0y1 = wz0 * wy1;                           \
        float tz1y0 = wz1 * wy0, tz1y1 = wz1 * wy1;                           \
        float w1 = tz0y0 * wx0, w2 = tz0y0 * wx1;                             \
        float w3 = tz0y1 * wx0, w4 = tz0y1 * wx1;                             \
        float w5 = tz1y0 * wx0, w6 = tz1y0 * wx1;                             \
        float w7 = tz1y1 * wx0, w8 = tz1y1 * wx1;                             \
        float acc_i = 0.0f;                                                   \
        acc_i = acc_i + ia00 * w1;                                            \
        acc_i = acc_i + ia10 * w2;                                            \
        acc_i = acc_i + ia01 * w3;                                            \
        acc_i = acc_i + ia11 * w4;                                            \
        acc_i = acc_i + ib00 * w5;                                            \
        acc_i = acc_i + ib10 * w6;                                            \
        acc_i = acc_i + ib01 * w7;                                            \
        acc_i = acc_i + ib11 * w8;                                            \
        float acc_l = 0.0f;                                                   \
        acc_l = acc_l + la00 * w1;                                            \
        acc_l = acc_l + la10 * w2;                                            \
        acc_l = acc_l + la01 * w3;                                            \
        acc_l = acc_l + la11 * w4;                                            \
        acc_l = acc_l + lb00 * w5;                                            \
        acc_l = acc_l + lb10 * w6;                                            \
        acc_l = acc_l + lb01 * w7;                                            \
        acc_l = acc_l + lb11 * w8;                                            \
        out_in[obase + (ZOFF)]  = acc_i;                                      \
        out_lab[obase + (ZOFF)] = (acc_l > 0.5f) ? 1.0f : 0.0f;               \
    }

    DO_Z(ze0, l)
    DO_Z(ze1, l + 64)
    #undef DO_Z
}

extern "C" void kernel_launch(void* const* d_in, const int* in_sizes, int n_in,
                              void* d_out, int out_size, void* d_ws, size_t ws_size,
                              hipStream_t stream) {
    const float* in  = (const float*)d_in[0];
    const float* lab = (const float*)d_in[1];
    const float* T   = (const float*)d_in[2];
    float* out_in  = (float*)d_out;
    float* out_lab = (float*)d_out + TOTAL;
    float* ws      = (float*)d_ws;              // needs 263168 B (257 KB)

    seg_aug_tables<<<dim3(129), dim3(128), 0, stream>>>(T, ws);
    // one wave per output column; 8 columns per 512-thread block
    seg_aug_kernel<<<dim3(TOTAL / NV / WPB), dim3(512), 0, stream>>>(
        in, lab, ws, out_in, out_lab);
}

// Round 4
// 235.118 us; speedup vs baseline: 1.0549x; 1.0111x over previous
//
#include <hip/hip_runtime.h>

// SegmentationAugmentation: fused affine-grid + trilinear grid_sample (border,
// align_corners=False) for input (float out) and label (bool-as-float out).
//
// R7: R6 (one independent wave per column, no barriers) put the kernel at
// ~75us (out of rocprof top-5; top-5 is now the harness's 2x80us output
// fills). Still ~1.8x above the 41us HBM floor with no pipe saturated ->
// per-wave serial structure: DMA-issue -> blanket vmcnt(0) -> compute. R7
// pipelines within the wave:
//  1) split-vmcnt: issue {ztable, inA, inB} then {labA, labB}; vmcnt(2) ->
//     input half computes/stores while label DMAs fly; vmcnt(1) (in-store is
//     the allowed outstanding op) -> label half. Wave-local, no barriers.
//  2) paired-z: lane does z=2l,2l+1 -> z-table is one dwordx4/lane, stores
//     are global_store_dwordx2 (512B/wave/inst); halves those inst counts.
//  3) label rows rebased to sw+516 with zeroed guards at sw[512] (input row3
//     one-past) and sw[1028] (label row3 one-past), so the input half never
//     touches the pending label region. Weights w1..w8 computed once per z,
//     reused by the label half (reference uses identical weights for both).
//
// Keeps the R4/R5/R6-validated z-edge elimination: read s[iz0], s[iz0+1]
// directly; at iz0==127 fz==+0 so z1-plane weights are +0 and the one-past
// value (next row's z0 or a zeroed guard) contributes +-0 — bit-identical
// to the reference's +0*s[127] (absmax 0.0 across R4/R5/R6).
//
// CORRECTNESS-CRITICAL: label output is a hard comparator (acc > 0.5) with
// voxels ~0.5 ulp from the boundary; all float math must stay bit-exact vs
// numpy: contract(off) in BOTH kernels, x/y/z paths verbatim in the table
// kernel, w = (wz*wy)*wx, reference corner accumulation order (z outer, y
// mid, x inner). Restructuring only changes where/when identical bits flow.

#define NV 128
#define TOTAL (8 * NV * NV * NV)
#define WPB 8                 // waves (= columns) per block
#define WSTRIDE 1032          // floats per wave region: in 0..511, guard 512,
                              // lab 516..1027, guard 1028 (+pad, 16B-aligned)

// ---- table-builder: block 128 = z-table, blocks 0..127 = xy-table ----
__global__ __launch_bounds__(128) void seg_aug_tables(
    const float* __restrict__ T, float* __restrict__ ws)
{
#pragma clang fp contract(off)
    const int t = threadIdx.x;
    if (blockIdx.x == 128) {
        // z-table entry t = {iz0, fz}; verbatim R3 z path
        float p4 = (2.0f * (float)t + 1.0f) / 128.0f - 1.0f;
        float uz = T[10] * p4 + T[11];
        float gz = ((uz + 1.0f) * 128.0f - 1.0f) * 0.5f;
        gz = fminf(fmaxf(gz, 0.0f), 127.0f);
        float fz0f = floorf(gz);
        float fz = gz - fz0f;
        int2 v;
        v.x = (int)fz0f;
        v.y = __float_as_int(fz);
        ((int2*)ws)[t] = v;
    } else {
        const int idx = blockIdx.x * 128 + t;   // 0..16383
        const int o3 = idx & (NV - 1);
        const int o2 = idx >> 7;
        // verbatim R3 x/y path
        float p2 = (2.0f * (float)o2 + 1.0f) / 128.0f - 1.0f;
        float p3 = (2.0f * (float)o3 + 1.0f) / 128.0f - 1.0f;
        float ux = (T[0] * p2 + T[1] * p3) + T[3];
        float uy = (T[4] * p2 + T[5] * p3) + T[7];
        float gx = ((ux + 1.0f) * 128.0f - 1.0f) * 0.5f;
        float gy = ((uy + 1.0f) * 128.0f - 1.0f) * 0.5f;
        gx = fminf(fmaxf(gx, 0.0f), 127.0f);
        gy = fminf(fmaxf(gy, 0.0f), 127.0f);
        float fx0f = floorf(gx), fy0f = floorf(gy);
        int4 v;
        v.x = (int)fx0f;
        v.y = (int)fy0f;
        v.z = __float_as_int(gx - fx0f);
        v.w = __float_as_int(gy - fy0f);
        ((int4*)(ws + 256))[idx] = v;           // +1024 bytes
    }
}

__global__ __launch_bounds__(512) void seg_aug_kernel(
    const float* __restrict__ in,
    const float* __restrict__ lab,
    const float* __restrict__ ws,  // tables (read-only here)
    float* __restrict__ out_in,
    float* __restrict__ out_lab)
{
#pragma clang fp contract(off)
    __shared__ __align__(16) float s[WPB * WSTRIDE];

    const int t = threadIdx.x;
    const int l = t & 63;                                   // lane
    const int w = __builtin_amdgcn_readfirstlane(t >> 6);   // wave id (uniform)
    const int col = (blockIdx.x << 3) | w;                  // global column
    const int b = col >> 14;

    // ---- column-uniform x/y from table (uniform -> s_load) ----
    const int4 e = ((const int4*)(ws + 256))[col & 16383];
    const int ix0 = __builtin_amdgcn_readfirstlane(e.x);
    const int iy0 = __builtin_amdgcn_readfirstlane(e.y);
    const float fx = __int_as_float(e.z);
    const float fy = __int_as_float(e.w);
    const int ix1 = min(ix0 + 1, NV - 1);
    const int iy1 = min(iy0 + 1, NV - 1);
    const int r00 = (ix0 * NV + iy0) * NV;
    const int r01 = (ix0 * NV + iy1) * NV;
    const int r10 = (ix1 * NV + iy0) * NV;
    const int r11 = (ix1 * NV + iy1) * NV;

    // per-lane DMA sources: inst A = rows {00,01}, inst B = rows {10,11}
    const int segoff = (l & 31) * 4;
    const int offA = ((l < 32) ? r00 : r01) + segoff;
    const int offB = ((l < 32) ? r10 : r11) + segoff;
    const size_t bbase = (size_t)b << 21;    // b * 128^3
    const float* ibp = in  + bbase;
    const float* lbp = lab + bbase;
    float* sw = &s[w * WSTRIDE];

    // ---- group 1 (oldest vmem ops): z-table pair + input DMAs ----
    const int4 zz = ((const int4*)ws)[l];    // z entries 2l, 2l+1
    __builtin_amdgcn_global_load_lds(ibp + offA, sw,       16, 0, 0);
    __builtin_amdgcn_global_load_lds(ibp + offB, sw + 256, 16, 0, 0);
    __builtin_amdgcn_sched_barrier(0);       // pin group order for vmcnt counting
    // ---- group 2: label DMAs ----
    __builtin_amdgcn_global_load_lds(lbp + offA, sw + 516, 16, 0, 0);
    __builtin_amdgcn_global_load_lds(lbp + offB, sw + 772, 16, 0, 0);

    if (l == 0) { sw[512] = 0.0f; sw[1028] = 0.0f; }   // finite one-past guards

    // ---- weights (zz-dependent VALU overlaps DMA latency) ----
    const float wx0 = 1.0f - fx, wx1 = fx;
    const float wy0 = 1.0f - fy, wy1 = fy;
    const int   iza = zz.x;
    const float fza = __int_as_float(zz.y);
    const int   izb = zz.z;
    const float fzb = __int_as_float(zz.w);

    const float awz0 = 1.0f - fza, awz1 = fza;
    float atz0y0 = awz0 * wy0, atz0y1 = awz0 * wy1;
    float atz1y0 = awz1 * wy0, atz1y1 = awz1 * wy1;
    float aw1 = atz0y0 * wx0, aw2 = atz0y0 * wx1;
    float aw3 = atz0y1 * wx0, aw4 = atz0y1 * wx1;
    float aw5 = atz1y0 * wx0, aw6 = atz1y0 * wx1;
    float aw7 = atz1y1 * wx0, aw8 = atz1y1 * wx1;

    const float bwz0 = 1.0f - fzb, bwz1 = fzb;
    float btz0y0 = bwz0 * wy0, btz0y1 = bwz0 * wy1;
    float btz1y0 = bwz1 * wy0, btz1y1 = bwz1 * wy1;
    float bw1 = btz0y0 * wx0, bw2 = btz0y0 * wx1;
    float bw3 = btz0y1 * wx0, bw4 = btz0y1 * wx1;
    float bw5 = btz1y0 * wx0, bw6 = btz1y0 * wx1;
    float bw7 = btz1y1 * wx0, bw8 = btz1y1 * wx1;

    const int obase = col * NV;

    // ==== input half: needs only {ztable, inA, inB} -> vmcnt(2) ====
    asm volatile("s_waitcnt vmcnt(2)" ::: "memory");
    __builtin_amdgcn_sched_barrier(0);
    {
        const float* rpa = sw + iza;
        float a00 = rpa[0*NV], a00p = rpa[0*NV+1];
        float a01 = rpa[1*NV], a01p = rpa[1*NV+1];
        float a10 = rpa[2*NV], a10p = rpa[2*NV+1];
        float a11 = rpa[3*NV], a11p = rpa[3*NV+1];
        float acc_a = 0.0f;
        acc_a = acc_a + a00  * aw1;
        acc_a = acc_a + a10  * aw2;
        acc_a = acc_a + a01  * aw3;
        acc_a = acc_a + a11  * aw4;
        acc_a = acc_a + a00p * aw5;
        acc_a = acc_a + a10p * aw6;
        acc_a = acc_a + a01p * aw7;
        acc_a = acc_a + a11p * aw8;

        const float* rpb = sw + izb;
        float c00 = rpb[0*NV], c00p = rpb[0*NV+1];
        float c01 = rpb[1*NV], c01p = rpb[1*NV+1];
        float c10 = rpb[2*NV], c10p = rpb[2*NV+1];
        float c11 = rpb[3*NV], c11p = rpb[3*NV+1];
        float acc_b = 0.0f;
        acc_b = acc_b + c00  * bw1;
        acc_b = acc_b + c10  * bw2;
        acc_b = acc_b + c01  * bw3;
        acc_b = acc_b + c11  * bw4;
        acc_b = acc_b + c00p * bw5;
        acc_b = acc_b + c10p * bw6;
        acc_b = acc_b + c01p * bw7;
        acc_b = acc_b + c11p * bw8;

        float2 v; v.x = acc_a; v.y = acc_b;
        ((float2*)(out_in + obase))[l] = v;      // 8B/lane, 512B/wave store
    }

    // ==== label half: labs are the oldest remaining; the in-store is the
    // one allowed outstanding op -> vmcnt(1) ====
    asm volatile("s_waitcnt vmcnt(1)" ::: "memory");
    __builtin_amdgcn_sched_barrier(0);
    {
        const float* lpa = sw + 516 + iza;
        float a00 = lpa[0*NV], a00p = lpa[0*NV+1];
        float a01 = lpa[1*NV], a01p = lpa[1*NV+1];
        float a10 = lpa[2*NV], a10p = lpa[2*NV+1];
        float a11 = lpa[3*NV], a11p = lpa[3*NV+1];
        float acc_a = 0.0f;
        acc_a = acc_a + a00  * aw1;
        acc_a = acc_a + a10  * aw2;
        acc_a = acc_a + a01  * aw3;
        acc_a = acc_a + a11  * aw4;
        acc_a = acc_a + a00p * aw5;
        acc_a = acc_a + a10p * aw6;
        acc_a = acc_a + a01p * aw7;
        acc_a = acc_a + a11p * aw8;

        const float* lpb = sw + 516 + izb;
        float c00 = lpb[0*NV], c00p = lpb[0*NV+1];
        float c01 = lpb[1*NV], c01p = lpb[1*NV+1];
        float c10 = lpb[2*NV], c10p = lpb[2*NV+1];
        float c11 = lpb[3*NV], c11p = lpb[3*NV+1];
        float acc_b = 0.0f;
        acc_b = acc_b + c00  * bw1;
        acc_b = acc_b + c10  * bw2;
        acc_b = acc_b + c01  * bw3;
        acc_b = acc_b + c11  * bw4;
        acc_b = acc_b + c00p * bw5;
        acc_b = acc_b + c10p * bw6;
        acc_b = acc_b + c01p * bw7;
        acc_b = acc_b + c11p * bw8;

        float2 v;
        v.x = (acc_a > 0.5f) ? 1.0f : 0.0f;
        v.y = (acc_b > 0.5f) ? 1.0f : 0.0f;
        ((float2*)(out_lab + obase))[l] = v;
    }
}

extern "C" void kernel_launch(void* const* d_in, const int* in_sizes, int n_in,
                              void* d_out, int out_size, void* d_ws, size_t ws_size,
                              hipStream_t stream) {
    const float* in  = (const float*)d_in[0];
    const float* lab = (const float*)d_in[1];
    const float* T   = (const float*)d_in[2];
    float* out_in  = (float*)d_out;
    float* out_lab = (float*)d_out + TOTAL;
    float* ws      = (float*)d_ws;              // needs 263168 B (257 KB)

    seg_aug_tables<<<dim3(129), dim3(128), 0, stream>>>(T, ws);
    // one wave per output column; 8 columns per 512-thread block
    seg_aug_kernel<<<dim3(TOTAL / NV / WPB), dim3(512), 0, stream>>>(
        in, lab, ws, out_in, out_lab);
}

// Round 5
// 229.788 us; speedup vs baseline: 1.0794x; 1.0232x over previous
//
#include <hip/hip_runtime.h>

// SegmentationAugmentation: fused affine-grid + trilinear grid_sample (border,
// align_corners=False) for input (float out) and label (bool-as-float out).
//
// R8: R7 post-mortem — split-vmcnt gained only ~2.5us; per-CU outstanding DMA
// already saturates the memory system, so MLP is not the lever. Remaining gap
// to the 41us byte-floor: (a) the serializing seg_aug_tables launch + bubble
// (~4-8us/iter) — R5 proved VALU is NOT binding (70->41% busy, time flat), so
// tables bought nothing but still cost a launch; (b) 134MB of output stores
// write-allocating in the 4MB/XCD L2s, evicting the live gather band. Fixes:
//  1) tables kernel deleted; xy/z math back in-kernel (verbatim R0-R4
//     expressions, validated bit-exact there). ~60 VALU/wave, absorbed at
//     ~40% VALUBusy; z math issued after the DMAs to overlap latency.
//  2) __builtin_nontemporal_store (nt) for both outputs: write stream
//     bypasses L2, freeing it for gather reuse.
//  3) vmcnt discipline unchanged from R7 (z-table load gone): issue
//     {inA,inB} then {labA,labB}; vmcnt(2) -> input half (labs in flight);
//     vmcnt(1) (in-store is the allowed outstanding op) -> label half.
// Structure otherwise R6/R7: one independent wave per output column, no
// barriers; paired-z (lane does z=2l,2l+1); 8 waves/block; 33KB LDS ->
// 4 blocks/CU = 32 waves/CU.
//
// Keeps the R4-R7-validated z-edge elimination: read s[iz0], s[iz0+1]
// directly; at iz0==127 fz==+0 so z1-plane weights are +0 and the one-past
// value (next row's z0 or a zeroed guard) contributes +-0 — bit-identical
// to the reference's +0*s[127] (absmax 0.0 across R4-R7).
//
// CORRECTNESS-CRITICAL: label output is a hard comparator (acc > 0.5) with
// voxels ~0.5 ulp from the boundary; all float math must stay bit-exact vs
// numpy: contract(off), x/y/z paths verbatim, w = (wz*wy)*wx, reference
// corner accumulation order (z outer, y mid, x inner). Restructuring only
// changes where/when identical bits flow.

#define NV 128
#define TOTAL (8 * NV * NV * NV)
#define WPB 8                 // waves (= columns) per block
#define WSTRIDE 1032          // floats per wave region: in 0..511, guard 512,
                              // lab 516..1027, guard 1028 (+pad, 16B-aligned)

typedef float v2f __attribute__((ext_vector_type(2)));

__global__ __launch_bounds__(512) void seg_aug_kernel(
    const float* __restrict__ in,
    const float* __restrict__ lab,
    const float* __restrict__ T,   // 16 floats, 4x4 row-major; rows 0..2 used
    float* __restrict__ out_in,
    float* __restrict__ out_lab)
{
#pragma clang fp contract(off)
    __shared__ __align__(16) float s[WPB * WSTRIDE];

    const int t = threadIdx.x;
    const int l = t & 63;                                   // lane
    const int w = __builtin_amdgcn_readfirstlane(t >> 6);   // wave id (uniform)
    const int col = (blockIdx.x << 3) | w;                  // global column
    const int o3 = col & (NV - 1);
    const int o2 = (col >> 7) & (NV - 1);
    const int b  = col >> 14;

    // ---- column-uniform x/y path (verbatim R3; T[i] are uniform s_loads) ----
    float p2 = (2.0f * (float)o2 + 1.0f) / 128.0f - 1.0f;
    float p3 = (2.0f * (float)o3 + 1.0f) / 128.0f - 1.0f;
    float ux = (T[0] * p2 + T[1] * p3) + T[3];
    float uy = (T[4] * p2 + T[5] * p3) + T[7];
    float gx = ((ux + 1.0f) * 128.0f - 1.0f) * 0.5f;
    float gy = ((uy + 1.0f) * 128.0f - 1.0f) * 0.5f;
    gx = fminf(fmaxf(gx, 0.0f), 127.0f);
    gy = fminf(fmaxf(gy, 0.0f), 127.0f);
    float fx0f = floorf(gx), fy0f = floorf(gy);
    float fx = gx - fx0f;
    float fy = gy - fy0f;
    const int ix0 = __builtin_amdgcn_readfirstlane((int)fx0f);
    const int iy0 = __builtin_amdgcn_readfirstlane((int)fy0f);
    const int ix1 = min(ix0 + 1, NV - 1);
    const int iy1 = min(iy0 + 1, NV - 1);
    const int r00 = (ix0 * NV + iy0) * NV;
    const int r01 = (ix0 * NV + iy1) * NV;
    const int r10 = (ix1 * NV + iy0) * NV;
    const int r11 = (ix1 * NV + iy1) * NV;

    // per-lane DMA sources: inst A = rows {00,01}, inst B = rows {10,11}
    // (when iy unclamped these are contiguous 1KB chunks)
    const int segoff = (l & 31) * 4;
    const int offA = ((l < 32) ? r00 : r01) + segoff;
    const int offB = ((l < 32) ? r10 : r11) + segoff;
    const size_t bbase = (size_t)b << 21;    // b * 128^3
    const float* ibp = in  + bbase;
    const float* lbp = lab + bbase;
    float* sw = &s[w * WSTRIDE];

    // ---- group 1 (oldest vmem ops): input DMAs ----
    __builtin_amdgcn_global_load_lds(ibp + offA, sw,       16, 0, 0);
    __builtin_amdgcn_global_load_lds(ibp + offB, sw + 256, 16, 0, 0);
    __builtin_amdgcn_sched_barrier(0);       // pin group order for vmcnt counting
    // ---- group 2: label DMAs ----
    __builtin_amdgcn_global_load_lds(lbp + offA, sw + 516, 16, 0, 0);
    __builtin_amdgcn_global_load_lds(lbp + offB, sw + 772, 16, 0, 0);

    if (l == 0) { sw[512] = 0.0f; sw[1028] = 0.0f; }   // finite one-past guards

    // ---- per-lane z path for z = 2l and 2l+1 (verbatim R3; overlaps DMA) ----
    float p4a = (2.0f * (float)(2 * l) + 1.0f) / 128.0f - 1.0f;
    float uza = T[10] * p4a + T[11];
    float gza = ((uza + 1.0f) * 128.0f - 1.0f) * 0.5f;
    gza = fminf(fmaxf(gza, 0.0f), 127.0f);
    float fz0a = floorf(gza);
    const int   iza = (int)fz0a;
    const float fza = gza - fz0a;

    float p4b = (2.0f * (float)(2 * l + 1) + 1.0f) / 128.0f - 1.0f;
    float uzb = T[10] * p4b + T[11];
    float gzb = ((uzb + 1.0f) * 128.0f - 1.0f) * 0.5f;
    gzb = fminf(fmaxf(gzb, 0.0f), 127.0f);
    float fz0b = floorf(gzb);
    const int   izb = (int)fz0b;
    const float fzb = gzb - fz0b;

    // ---- weights (VALU overlaps DMA latency) ----
    const float wx0 = 1.0f - fx, wx1 = fx;
    const float wy0 = 1.0f - fy, wy1 = fy;

    const float awz0 = 1.0f - fza, awz1 = fza;
    float atz0y0 = awz0 * wy0, atz0y1 = awz0 * wy1;
    float atz1y0 = awz1 * wy0, atz1y1 = awz1 * wy1;
    float aw1 = atz0y0 * wx0, aw2 = atz0y0 * wx1;
    float aw3 = atz0y1 * wx0, aw4 = atz0y1 * wx1;
    float aw5 = atz1y0 * wx0, aw6 = atz1y0 * wx1;
    float aw7 = atz1y1 * wx0, aw8 = atz1y1 * wx1;

    const float bwz0 = 1.0f - fzb, bwz1 = fzb;
    float btz0y0 = bwz0 * wy0, btz0y1 = bwz0 * wy1;
    float btz1y0 = bwz1 * wy0, btz1y1 = bwz1 * wy1;
    float bw1 = btz0y0 * wx0, bw2 = btz0y0 * wx1;
    float bw3 = btz0y1 * wx0, bw4 = btz0y1 * wx1;
    float bw5 = btz1y0 * wx0, bw6 = btz1y0 * wx1;
    float bw7 = btz1y1 * wx0, bw8 = btz1y1 * wx1;

    const int obase = col * NV;

    // ==== input half: needs only {inA, inB} -> vmcnt(2) ====
    asm volatile("s_waitcnt vmcnt(2)" ::: "memory");
    __builtin_amdgcn_sched_barrier(0);
    {
        const float* rpa = sw + iza;
        float a00 = rpa[0*NV], a00p = rpa[0*NV+1];
        float a01 = rpa[1*NV], a01p = rpa[1*NV+1];
        float a10 = rpa[2*NV], a10p = rpa[2*NV+1];
        float a11 = rpa[3*NV], a11p = rpa[3*NV+1];
        float acc_a = 0.0f;
        acc_a = acc_a + a00  * aw1;
        acc_a = acc_a + a10  * aw2;
        acc_a = acc_a + a01  * aw3;
        acc_a = acc_a + a11  * aw4;
        acc_a = acc_a + a00p * aw5;
        acc_a = acc_a + a10p * aw6;
        acc_a = acc_a + a01p * aw7;
        acc_a = acc_a + a11p * aw8;

        const float* rpb = sw + izb;
        float c00 = rpb[0*NV], c00p = rpb[0*NV+1];
        float c01 = rpb[1*NV], c01p = rpb[1*NV+1];
        float c10 = rpb[2*NV], c10p = rpb[2*NV+1];
        float c11 = rpb[3*NV], c11p = rpb[3*NV+1];
        float acc_b = 0.0f;
        acc_b = acc_b + c00  * bw1;
        acc_b = acc_b + c10  * bw2;
        acc_b = acc_b + c01  * bw3;
        acc_b = acc_b + c11  * bw4;
        acc_b = acc_b + c00p * bw5;
        acc_b = acc_b + c10p * bw6;
        acc_b = acc_b + c01p * bw7;
        acc_b = acc_b + c11p * bw8;

        v2f v; v.x = acc_a; v.y = acc_b;
        __builtin_nontemporal_store(v, (v2f*)(out_in + obase) + l);
    }

    // ==== label half: labs are the oldest remaining; the in-store is the
    // one allowed outstanding op -> vmcnt(1) ====
    asm volatile("s_waitcnt vmcnt(1)" ::: "memory");
    __builtin_amdgcn_sched_barrier(0);
    {
        const float* lpa = sw + 516 + iza;
        float a00 = lpa[0*NV], a00p = lpa[0*NV+1];
        float a01 = lpa[1*NV], a01p = lpa[1*NV+1];
        float a10 = lpa[2*NV], a10p = lpa[2*NV+1];
        float a11 = lpa[3*NV], a11p = lpa[3*NV+1];
        float acc_a = 0.0f;
        acc_a = acc_a + a00  * aw1;
        acc_a = acc_a + a10  * aw2;
        acc_a = acc_a + a01  * aw3;
        acc_a = acc_a + a11  * aw4;
        acc_a = acc_a + a00p * aw5;
        acc_a = acc_a + a10p * aw6;
        acc_a = acc_a + a01p * aw7;
        acc_a = acc_a + a11p * aw8;

        const float* lpb = sw + 516 + izb;
        float c00 = lpb[0*NV], c00p = lpb[0*NV+1];
        float c01 = lpb[1*NV], c01p = lpb[1*NV+1];
        float c10 = lpb[2*NV], c10p = lpb[2*NV+1];
        float c11 = lpb[3*NV], c11p = lpb[3*NV+1];
        float acc_b = 0.0f;
        acc_b = acc_b + c00  * bw1;
        acc_b = acc_b + c10  * bw2;
        acc_b = acc_b + c01  * bw3;
        acc_b = acc_b + c11  * bw4;
        acc_b = acc_b + c00p * bw5;
        acc_b = acc_b + c10p * bw6;
        acc_b = acc_b + c01p * bw7;
        acc_b = acc_b + c11p * bw8;

        v2f v;
        v.x = (acc_a > 0.5f) ? 1.0f : 0.0f;
        v.y = (acc_b > 0.5f) ? 1.0f : 0.0f;
        __builtin_nontemporal_store(v, (v2f*)(out_lab + obase) + l);
    }
}

extern "C" void kernel_launch(void* const* d_in, const int* in_sizes, int n_in,
                              void* d_out, int out_size, void* d_ws, size_t ws_size,
                              hipStream_t stream) {
    const float* in  = (const float*)d_in[0];
    const float* lab = (const float*)d_in[1];
    const float* T   = (const float*)d_in[2];
    float* out_in  = (float*)d_out;
    float* out_lab = (float*)d_out + TOTAL;

    // single kernel; one wave per output column; 8 columns per 512-thread block
    seg_aug_kernel<<<dim3(TOTAL / NV / WPB), dim3(512), 0, stream>>>(
        in, lab, T, out_in, out_lab);
}